// Round 8
// baseline (394.127 us; speedup 1.0000x reference)
//
#include <hip/hip_runtime.h>
#include <hip/hip_bf16.h>

#define NN 100000
#define EE 800000
#define GG 1024
#define ETOT (EE + NN)

typedef __attribute__((ext_vector_type(8))) short short8;
typedef __attribute__((ext_vector_type(4))) float floatx4;

__device__ __forceinline__ float sigmoidf_(float v) { return 1.f / (1.f + expf(-v)); }
__device__ __forceinline__ float bflo(unsigned int u) {
    union { unsigned int i; float f; } x; x.i = u << 16; return x.f;
}
__device__ __forceinline__ float bfhi(unsigned int u) {
    union { unsigned int i; float f; } x; x.i = u & 0xffff0000u; return x.f;
}
__device__ __forceinline__ unsigned short f2bf(float f) {
    union { unsigned int i; float f; } x; x.f = f;
    unsigned int r = (x.i + 0x7fff + ((x.i >> 16) & 1)) >> 16;
    return (unsigned short)r;
}
__device__ __forceinline__ unsigned pack2bf(float a, float b) {
    return (unsigned)f2bf(a) | ((unsigned)f2bf(b) << 16);
}
__device__ __forceinline__ float rl_f(float v, int j) {
    return __int_as_float(__builtin_amdgcn_readlane(__float_as_int(v), j));
}
__device__ __forceinline__ int rl_i(int v, int j) {
    return __builtin_amdgcn_readlane(v, j);
}
__device__ __forceinline__ float rfl_f(float v) {
    return __int_as_float(__builtin_amdgcn_readfirstlane(__float_as_int(v)));
}
__device__ __forceinline__ float lrelu(float e) { return (e > 0.f) ? e : 0.2f * e; }

// ---------------- init ----------------
__global__ void k_zero(int* deg, int* cur, float* gsum) {
    int i = blockIdx.x * 256 + threadIdx.x;
    if (i < NN) { deg[i] = 0; cur[i] = 0; }
    if (i < GG * 64) gsum[i] = 0.f;
}

// ---------------- precompute: embeddings + weights -> bf16 ----------------
__global__ void k_prep_emb(const float* __restrict__ e0, const float* __restrict__ e1,
                           const float* __restrict__ e2, const float* __restrict__ e3,
                           const float* __restrict__ e4, const float* __restrict__ e5,
                           unsigned short* __restrict__ ebf) {
    int i = blockIdx.x * 256 + threadIdx.x;
    if (i >= 50 * 64) return;
    int row = i >> 6, c = i & 63;
    const float* tab; int r;
    if (row < 33)      { tab = e0; r = row; }
    else if (row < 38) { tab = e1; r = row - 33; }
    else if (row < 41) { tab = e2; r = row - 38; }
    else if (row < 45) { tab = e3; r = row - 41; }
    else if (row < 47) { tab = e4; r = row - 45; }
    else               { tab = e5; r = row - 47; }
    ebf[i] = f2bf(tab[r * 64 + c]);
}

// W [K][256] f32 -> frag-ordered bf16: Wt[((ks*16+cf)*64 + lane)*8 + j]
template <int KS>
__global__ void k_prep_w(const float* __restrict__ W, unsigned short* __restrict__ Wt) {
    int tid = blockIdx.x * 256 + threadIdx.x;
    if (tid >= KS * 16 * 64) return;
    int l = tid & 63;
    int cf = (tid >> 6) & 15;
    int ks = tid >> 10;
    int kbase = ks * 32 + (l >> 4) * 8;
    int col = cf * 16 + (l & 15);
    unsigned short* o = Wt + (size_t)tid * 8;
#pragma unroll
    for (int j = 0; j < 8; j++) o[j] = f2bf(W[(size_t)(kbase + j) * 256 + col]);
}

// ---------------- CSR build ----------------
__global__ void k_hist(const int* __restrict__ ei, int* __restrict__ deg) {
    int e = blockIdx.x * 256 + threadIdx.x;
    if (e >= ETOT) return;
    int d = (e < EE) ? ei[EE + e] : (e - EE);
    atomicAdd(&deg[d], 1);
}

__global__ void k_scan1(const int* __restrict__ deg, int* __restrict__ offs,
                        int* __restrict__ bsum) {
    __shared__ int l[256];
    int i = blockIdx.x * 256 + threadIdx.x;
    l[threadIdx.x] = (i < NN) ? deg[i] : 0;
    __syncthreads();
    if (threadIdx.x == 0) {
        int run = 0;
        for (int j = 0; j < 256; j++) { int t = l[j]; l[j] = run; run += t; }
        bsum[blockIdx.x] = run;
    }
    __syncthreads();
    if (i < NN) offs[i] = l[threadIdx.x];
}

__global__ void k_scan2(int* __restrict__ bsum, int nb, int* __restrict__ offs) {
    int lane = threadIdx.x;  // 64 threads
    int run = 0;
    for (int base = 0; base < nb; base += 64) {
        int i = base + lane;
        int orig = (i < nb) ? bsum[i] : 0;
        int v = orig;
#pragma unroll
        for (int o = 1; o < 64; o <<= 1) {
            int t = __shfl_up(v, o);
            if (lane >= o) v += t;
        }
        if (i < nb) bsum[i] = run + v - orig;   // exclusive
        run += __shfl(v, 63);
    }
    if (lane == 0) offs[NN] = run;
}

__global__ void k_scan3(int* __restrict__ offs, const int* __restrict__ bsum) {
    int i = blockIdx.x * 256 + threadIdx.x;
    if (i < NN) offs[i] += bsum[blockIdx.x];
}

__global__ void k_scatter(const int* __restrict__ ei, const int* __restrict__ offs,
                          int* __restrict__ cur, int* __restrict__ csrc) {
    int e = blockIdx.x * 256 + threadIdx.x;
    if (e >= ETOT) return;
    int s, d;
    if (e < EE) { s = ei[e]; d = ei[EE + e]; }
    else { s = e - EE; d = e - EE; }
    int p = atomicAdd(&cur[d], 1);
    csrc[offs[d] + p] = s;
}

// ---------------- bf16 MFMA GEMM: C[M,256] = A[M,K] @ W[K,256] ----------------
template <int MODE, int KSTEPS>
__global__ __launch_bounds__(256) void k_gemm_mfma(const int* __restrict__ x,
                                                   const unsigned short* __restrict__ ebf,
                                                   const unsigned short* __restrict__ Abf,
                                                   const unsigned short* __restrict__ Wt,
                                                   unsigned short* __restrict__ Cb, int M) {
    __shared__ __align__(16) unsigned short As[128 * 40];
    int tid = threadIdx.x;
    int rowBase = blockIdx.y * 128;
    int colBase = blockIdx.x * 64;
    int l = tid & 63, w = tid >> 6;
    int strip = w * 32;
    floatx4 acc[2][4] = {};

    for (int ks = 0; ks < KSTEPS; ks++) {
        {
            int r = tid >> 1, half = tid & 1;
            int row = rowBase + r;
            uint4 v0 = {0, 0, 0, 0}, v1 = {0, 0, 0, 0};
            if (row < M) {
                const unsigned short* src;
                if (MODE == 0) {
                    int t = ks >> 1, cb = (ks & 1) * 32;
                    int toff = (t == 0) ? 0 : (t == 1) ? 33 : (t == 2) ? 38
                             : (t == 3) ? 41 : (t == 4) ? 45 : 47;
                    int vi = x[row * 6 + t];
                    src = ebf + (size_t)(toff + vi) * 64 + cb + half * 16;
                } else {
                    src = Abf + (size_t)row * 128 + ks * 32 + half * 16;
                }
                v0 = *(const uint4*)src;
                v1 = *(const uint4*)(src + 8);
            }
            uint4* dst = (uint4*)&As[r * 40 + half * 16];
            dst[0] = v0; dst[1] = v1;
        }
        __syncthreads();
        short8 a0 = *(const short8*)&As[(strip + (l & 15)) * 40 + (l >> 4) * 8];
        short8 a1 = *(const short8*)&As[(strip + 16 + (l & 15)) * 40 + (l >> 4) * 8];
        const short8* bp = (const short8*)(Wt + ((size_t)(ks * 16 + (colBase >> 4)) * 64 + l) * 8);
#pragma unroll
        for (int cf = 0; cf < 4; cf++) {
            short8 b = bp[cf * 64];
            acc[0][cf] = __builtin_amdgcn_mfma_f32_16x16x32_bf16(a0, b, acc[0][cf], 0, 0, 0);
            acc[1][cf] = __builtin_amdgcn_mfma_f32_16x16x32_bf16(a1, b, acc[1][cf], 0, 0, 0);
        }
        __syncthreads();
    }
#pragma unroll
    for (int rf = 0; rf < 2; rf++)
#pragma unroll
        for (int cf = 0; cf < 4; cf++)
#pragma unroll
            for (int i = 0; i < 4; i++) {
                int row = rowBase + strip + rf * 16 + (l >> 4) * 4 + i;
                int col = colBase + cf * 16 + (l & 15);
                if (row < M) Cb[(size_t)row * 256 + col] = f2bf(acc[rf][cf][i]);
            }
}

// ------- attention dots, wave-per-node: H heads, 256 total channels -------
template <int H>
__global__ __launch_bounds__(256) void k_sd2(const unsigned short* __restrict__ xwb,
                                             const float* __restrict__ a_src,
                                             const float* __restrict__ a_dst,
                                             float* __restrict__ s, float* __restrict__ dv) {
    const int G = 64 / H;           // lanes per head group
    int wv = threadIdx.x >> 6, lane = threadIdx.x & 63;
    int n = blockIdx.x * 4 + wv;    // grid = 25000 -> exact
    uint2 v = *(const uint2*)(xwb + (size_t)n * 256 + lane * 4);
    float4 as = ((const float4*)a_src)[lane];
    float4 ad = ((const float4*)a_dst)[lane];
    float f0 = bflo(v.x), f1 = bfhi(v.x), f2 = bflo(v.y), f3 = bfhi(v.y);
    float vs = f0 * as.x + f1 * as.y + f2 * as.z + f3 * as.w;
    float vd = f0 * ad.x + f1 * ad.y + f2 * ad.z + f3 * ad.w;
#pragma unroll
    for (int o = G / 2; o; o >>= 1) {
        vs += __shfl_xor(vs, o);
        vd += __shfl_xor(vd, o);
    }
    if ((lane & (G - 1)) == 0) {
        int h = lane / G;
        s[n * H + h] = vs;
        dv[n * H + h] = vd;
    }
}

// ------- layer-1 aggregation: uint4 2-edge gather + LDS weights -------
__global__ __launch_bounds__(256) void k_agg1(const unsigned short* __restrict__ xwb,
                                              const float* __restrict__ s,
                                              const float* __restrict__ dvec,
                                              const int* __restrict__ offs,
                                              const int* __restrict__ csrc,
                                              const float* __restrict__ b1,
                                              unsigned short* __restrict__ h1b) {
    __shared__ __align__(16) float2 wl[4][64];
    int wv = threadIdx.x >> 6, lane = threadIdx.x & 63;
    int n = blockIdx.x * 4 + wv;
    int half = lane >> 5, sub = lane & 31;
    int hh = sub >> 4;                      // head owning this lane's channels
    unsigned voff = (unsigned)sub * 16u;    // byte offset within 512B row
    const char* wbytes = (const char*)&wl[wv][0] + half * 8 + (hh << 2);
    const char* xb = (const char*)xwb;
    int start = offs[n], end = offs[n + 1], deg = end - start;
    float2 dn = *(const float2*)(dvec + n * 2);
    float acc[8] = {};
    float ws0, ws1;

    auto body = [&](int j, int sn) {
        unsigned offa = (unsigned)rl_i(sn, j) << 9;
        unsigned offb = (unsigned)rl_i(sn, j + 1) << 9;
        unsigned off = (half ? offb : offa) + voff;
        uint4 v = *(const uint4*)(xb + off);
        float w = *(const float*)(wbytes + j * 8);
        acc[0] += w * bflo(v.x); acc[1] += w * bfhi(v.x);
        acc[2] += w * bflo(v.y); acc[3] += w * bfhi(v.y);
        acc[4] += w * bflo(v.z); acc[5] += w * bfhi(v.z);
        acc[6] += w * bflo(v.w); acc[7] += w * bfhi(v.w);
    };

    if (deg <= 64) {
        int sn = 0; float e0 = -1e30f, e1 = -1e30f;
        if (lane < deg) {
            sn = csrc[start + lane];
            float2 sv = *(const float2*)(s + sn * 2);
            e0 = lrelu(sv.x + dn.x);
            e1 = lrelu(sv.y + dn.y);
        }
        float m0 = e0, m1 = e1;
        if (deg <= 16) {
#pragma unroll
            for (int o = 8; o; o >>= 1) {
                m0 = fmaxf(m0, __shfl_xor(m0, o));
                m1 = fmaxf(m1, __shfl_xor(m1, o));
            }
        } else {
#pragma unroll
            for (int o = 32; o; o >>= 1) {
                m0 = fmaxf(m0, __shfl_xor(m0, o));
                m1 = fmaxf(m1, __shfl_xor(m1, o));
            }
        }
        float w0 = (lane < deg) ? __expf(e0 - m0) : 0.f;
        float w1 = (lane < deg) ? __expf(e1 - m1) : 0.f;
        wl[wv][lane] = make_float2(w0, w1);
        ws0 = w0; ws1 = w1;
        if (deg <= 16) {
#pragma unroll
            for (int o = 8; o; o >>= 1) {
                ws0 += __shfl_xor(ws0, o);
                ws1 += __shfl_xor(ws1, o);
            }
            ws0 = rfl_f(ws0); ws1 = rfl_f(ws1);
        } else {
#pragma unroll
            for (int o = 32; o; o >>= 1) {
                ws0 += __shfl_xor(ws0, o);
                ws1 += __shfl_xor(ws1, o);
            }
        }
        int cnt2 = (deg + 1) & ~1;
        int j = 0;
        for (; j + 4 <= cnt2; j += 4) { body(j, sn); body(j + 2, sn); }
        for (; j < cnt2; j += 2) body(j, sn);
    } else {
        float m0 = -1e30f, m1 = -1e30f;
        for (int i = start + lane; i < end; i += 64) {
            int s2 = csrc[i];
            float2 sv = *(const float2*)(s + s2 * 2);
            m0 = fmaxf(m0, lrelu(sv.x + dn.x));
            m1 = fmaxf(m1, lrelu(sv.y + dn.y));
        }
#pragma unroll
        for (int o = 32; o; o >>= 1) {
            m0 = fmaxf(m0, __shfl_xor(m0, o));
            m1 = fmaxf(m1, __shfl_xor(m1, o));
        }
        float wa0 = 0.f, wa1 = 0.f;
        for (int base = start; base < end; base += 64) {
            int cnt = min(64, end - base);
            int sn = 0; float w0 = 0.f, w1 = 0.f;
            if (lane < cnt) {
                sn = csrc[base + lane];
                float2 sv = *(const float2*)(s + sn * 2);
                w0 = __expf(lrelu(sv.x + dn.x) - m0);
                w1 = __expf(lrelu(sv.y + dn.y) - m1);
            }
            wl[wv][lane] = make_float2(w0, w1);
            wa0 += w0; wa1 += w1;
            int cnt2 = (cnt + 1) & ~1;
            int j = 0;
            for (; j + 4 <= cnt2; j += 4) { body(j, sn); body(j + 2, sn); }
            for (; j < cnt2; j += 2) body(j, sn);
        }
        ws0 = wa0; ws1 = wa1;
#pragma unroll
        for (int o = 32; o; o >>= 1) {
            ws0 += __shfl_xor(ws0, o);
            ws1 += __shfl_xor(ws1, o);
        }
    }
    float inv = hh ? (1.f / (ws1 + 1e-16f)) : (1.f / (ws0 + 1e-16f));
    float hm[8];
#pragma unroll
    for (int k = 0; k < 8; k++) {
        acc[k] *= inv;
        acc[k] += __shfl_xor(acc[k], 32);   // merge the two edge-halves
        hm[k] = 0.5f * (acc[k] + __shfl_xor(acc[k], 16));  // head mean
    }
    if (lane < 16) {
        float4 ba = *(const float4*)(b1 + lane * 8);
        float4 bb = *(const float4*)(b1 + lane * 8 + 4);
        uint4 st;
        st.x = pack2bf(sigmoidf_(hm[0] + ba.x), sigmoidf_(hm[1] + ba.y));
        st.y = pack2bf(sigmoidf_(hm[2] + ba.z), sigmoidf_(hm[3] + ba.w));
        st.z = pack2bf(sigmoidf_(hm[4] + bb.x), sigmoidf_(hm[5] + bb.y));
        st.w = pack2bf(sigmoidf_(hm[6] + bb.z), sigmoidf_(hm[7] + bb.w));
        *(uint4*)(h1b + (size_t)n * 128 + lane * 8) = st;
    }
}

// ------- layer-2 aggregation: uint4 2-edge gather + LDS weights + pool -------
__global__ __launch_bounds__(256) void k_agg2(const unsigned short* __restrict__ xwb,
                                              const float* __restrict__ s,
                                              const float* __restrict__ dvec,
                                              const int* __restrict__ offs,
                                              const int* __restrict__ csrc,
                                              const float* __restrict__ b2,
                                              const int* __restrict__ batch,
                                              float* __restrict__ gsum) {
    __shared__ __align__(16) float4 wl[4][64];
    int wv = threadIdx.x >> 6, lane = threadIdx.x & 63;
    int n = blockIdx.x * 4 + wv;
    int half = lane >> 5, sub = lane & 31;
    int hh = sub >> 3;                      // head owning this lane's channels
    unsigned voff = (unsigned)sub * 16u;
    const char* wbytes = (const char*)&wl[wv][0] + half * 16 + (hh << 2);
    const char* xb = (const char*)xwb;
    int start = offs[n], end = offs[n + 1], deg = end - start;
    float4 dn = *(const float4*)(dvec + n * 4);
    float acc[8] = {};
    float ws0, ws1, ws2, ws3;

    auto body = [&](int j, int sn) {
        unsigned offa = (unsigned)rl_i(sn, j) << 9;
        unsigned offb = (unsigned)rl_i(sn, j + 1) << 9;
        unsigned off = (half ? offb : offa) + voff;
        uint4 v = *(const uint4*)(xb + off);
        float w = *(const float*)(wbytes + j * 16);
        acc[0] += w * bflo(v.x); acc[1] += w * bfhi(v.x);
        acc[2] += w * bflo(v.y); acc[3] += w * bfhi(v.y);
        acc[4] += w * bflo(v.z); acc[5] += w * bfhi(v.z);
        acc[6] += w * bflo(v.w); acc[7] += w * bfhi(v.w);
    };

    if (deg <= 64) {
        int sn = 0;
        float e0 = -1e30f, e1 = -1e30f, e2 = -1e30f, e3 = -1e30f;
        if (lane < deg) {
            sn = csrc[start + lane];
            float4 sv = *(const float4*)(s + sn * 4);
            e0 = lrelu(sv.x + dn.x); e1 = lrelu(sv.y + dn.y);
            e2 = lrelu(sv.z + dn.z); e3 = lrelu(sv.w + dn.w);
        }
        float m0 = e0, m1 = e1, m2 = e2, m3 = e3;
        if (deg <= 16) {
#pragma unroll
            for (int o = 8; o; o >>= 1) {
                m0 = fmaxf(m0, __shfl_xor(m0, o)); m1 = fmaxf(m1, __shfl_xor(m1, o));
                m2 = fmaxf(m2, __shfl_xor(m2, o)); m3 = fmaxf(m3, __shfl_xor(m3, o));
            }
        } else {
#pragma unroll
            for (int o = 32; o; o >>= 1) {
                m0 = fmaxf(m0, __shfl_xor(m0, o)); m1 = fmaxf(m1, __shfl_xor(m1, o));
                m2 = fmaxf(m2, __shfl_xor(m2, o)); m3 = fmaxf(m3, __shfl_xor(m3, o));
            }
        }
        float w0 = 0.f, w1 = 0.f, w2 = 0.f, w3 = 0.f;
        if (lane < deg) {
            w0 = __expf(e0 - m0); w1 = __expf(e1 - m1);
            w2 = __expf(e2 - m2); w3 = __expf(e3 - m3);
        }
        wl[wv][lane] = make_float4(w0, w1, w2, w3);
        ws0 = w0; ws1 = w1; ws2 = w2; ws3 = w3;
        if (deg <= 16) {
#pragma unroll
            for (int o = 8; o; o >>= 1) {
                ws0 += __shfl_xor(ws0, o); ws1 += __shfl_xor(ws1, o);
                ws2 += __shfl_xor(ws2, o); ws3 += __shfl_xor(ws3, o);
            }
            ws0 = rfl_f(ws0); ws1 = rfl_f(ws1);
            ws2 = rfl_f(ws2); ws3 = rfl_f(ws3);
        } else {
#pragma unroll
            for (int o = 32; o; o >>= 1) {
                ws0 += __shfl_xor(ws0, o); ws1 += __shfl_xor(ws1, o);
                ws2 += __shfl_xor(ws2, o); ws3 += __shfl_xor(ws3, o);
            }
        }
        int cnt2 = (deg + 1) & ~1;
        int j = 0;
        for (; j + 4 <= cnt2; j += 4) { body(j, sn); body(j + 2, sn); }
        for (; j < cnt2; j += 2) body(j, sn);
    } else {
        float m0 = -1e30f, m1 = -1e30f, m2 = -1e30f, m3 = -1e30f;
        for (int i = start + lane; i < end; i += 64) {
            int s2 = csrc[i];
            float4 sv = *(const float4*)(s + s2 * 4);
            m0 = fmaxf(m0, lrelu(sv.x + dn.x)); m1 = fmaxf(m1, lrelu(sv.y + dn.y));
            m2 = fmaxf(m2, lrelu(sv.z + dn.z)); m3 = fmaxf(m3, lrelu(sv.w + dn.w));
        }
#pragma unroll
        for (int o = 32; o; o >>= 1) {
            m0 = fmaxf(m0, __shfl_xor(m0, o)); m1 = fmaxf(m1, __shfl_xor(m1, o));
            m2 = fmaxf(m2, __shfl_xor(m2, o)); m3 = fmaxf(m3, __shfl_xor(m3, o));
        }
        float wa0 = 0.f, wa1 = 0.f, wa2 = 0.f, wa3 = 0.f;
        for (int base = start; base < end; base += 64) {
            int cnt = min(64, end - base);
            int sn = 0; float w0 = 0.f, w1 = 0.f, w2 = 0.f, w3 = 0.f;
            if (lane < cnt) {
                sn = csrc[base + lane];
                float4 sv = *(const float4*)(s + sn * 4);
                w0 = __expf(lrelu(sv.x + dn.x) - m0);
                w1 = __expf(lrelu(sv.y + dn.y) - m1);
                w2 = __expf(lrelu(sv.z + dn.z) - m2);
                w3 = __expf(lrelu(sv.w + dn.w) - m3);
            }
            wl[wv][lane] = make_float4(w0, w1, w2, w3);
            wa0 += w0; wa1 += w1; wa2 += w2; wa3 += w3;
            int cnt2 = (cnt + 1) & ~1;
            int j = 0;
            for (; j + 4 <= cnt2; j += 4) { body(j, sn); body(j + 2, sn); }
            for (; j < cnt2; j += 2) body(j, sn);
        }
        ws0 = wa0; ws1 = wa1; ws2 = wa2; ws3 = wa3;
#pragma unroll
        for (int o = 32; o; o >>= 1) {
            ws0 += __shfl_xor(ws0, o); ws1 += __shfl_xor(ws1, o);
            ws2 += __shfl_xor(ws2, o); ws3 += __shfl_xor(ws3, o);
        }
    }
    float wsel = (hh & 2) ? ((hh & 1) ? ws3 : ws2) : ((hh & 1) ? ws1 : ws0);
    float inv = 1.f / (wsel + 1e-16f);
#pragma unroll
    for (int k = 0; k < 8; k++) {
        acc[k] *= inv;
        acc[k] += __shfl_xor(acc[k], 32);   // merge edge-halves
        acc[k] += __shfl_xor(acc[k], 8);    // head0+head1, head2+head3
        acc[k] += __shfl_xor(acc[k], 16);   // all 4 heads
    }
    // lanes 0-7 hold sum over heads for channels (lane)*8 + k
    float* fs = (float*)&wl[wv][0];
    if (lane < 8) {
        *(float4*)(fs + lane * 8)     = make_float4(acc[0], acc[1], acc[2], acc[3]);
        *(float4*)(fs + lane * 8 + 4) = make_float4(acc[4], acc[5], acc[6], acc[7]);
    }
    float vv = 0.25f * fs[lane] + b2[lane];
    atomicAdd(&gsum[(size_t)batch[n] * 64 + lane], sigmoidf_(vv));
}

// ---------------- final ----------------
__global__ void k_final(const float* __restrict__ gsum, const float* __restrict__ lw,
                        const float* __restrict__ lb, float* __restrict__ out) {
    int g = blockIdx.x;
    int lane = threadIdx.x;
    float v = gsum[g * 64 + lane] * lw[lane];
    for (int o = 32; o; o >>= 1) v += __shfl_down(v, o);
    if (lane == 0) out[g] = sigmoidf_(v + lb[0]);
}

// ---------------- launch ----------------
extern "C" void kernel_launch(void* const* d_in, const int* in_sizes, int n_in,
                              void* d_out, int out_size, void* d_ws, size_t ws_size,
                              hipStream_t stream) {
    const int* x   = (const int*)d_in[0];
    const int* ei  = (const int*)d_in[1];
    const int* bat = (const int*)d_in[3];
    const float* e0 = (const float*)d_in[4];
    const float* e1 = (const float*)d_in[5];
    const float* e2 = (const float*)d_in[6];
    const float* e3 = (const float*)d_in[7];
    const float* e4 = (const float*)d_in[8];
    const float* e5 = (const float*)d_in[9];
    const float* W1 = (const float*)d_in[10];
    const float* as1 = (const float*)d_in[11];
    const float* ad1 = (const float*)d_in[12];
    const float* b1 = (const float*)d_in[13];
    const float* W2 = (const float*)d_in[14];
    const float* as2 = (const float*)d_in[15];
    const float* ad2 = (const float*)d_in[16];
    const float* b2 = (const float*)d_in[17];
    const float* lw = (const float*)d_in[18];
    const float* lb = (const float*)d_in[19];
    float* out = (float*)d_out;

    char* base = (char*)d_ws;
    size_t off = 0;
    auto alloc = [&](size_t bytes) {
        size_t o = off;
        off = (off + bytes + 255) & ~(size_t)255;
        return o;
    };
    unsigned short* xwb = (unsigned short*)(base + alloc((size_t)NN * 256 * 2));
    unsigned short* h1b = (unsigned short*)(base + alloc((size_t)NN * 128 * 2));
    float* sbuf = (float*)(base + alloc((size_t)NN * 4 * 4));
    float* dbuf = (float*)(base + alloc((size_t)NN * 4 * 4));
    float* gsum = (float*)(base + alloc((size_t)GG * 64 * 4));
    int* deg  = (int*)(base + alloc((size_t)NN * 4));
    int* offs = (int*)(base + alloc((size_t)(NN + 1) * 4));
    int* cur  = (int*)(base + alloc((size_t)NN * 4));
    int* csrc = (int*)(base + alloc((size_t)ETOT * 4));
    int* bsum = (int*)(base + alloc((size_t)512 * 4));
    unsigned short* ebf = (unsigned short*)(base + alloc((size_t)50 * 64 * 2));
    unsigned short* Wt1 = (unsigned short*)(base + alloc((size_t)384 * 256 * 2));
    unsigned short* Wt2 = (unsigned short*)(base + alloc((size_t)128 * 256 * 2));

    const int nb = (NN + 255) / 256;  // 391
    const int nwb = NN / 4;           // 25000 wave-per-node blocks

    k_zero<<<nb, 256, 0, stream>>>(deg, cur, gsum);
    k_prep_emb<<<(50 * 64 + 255) / 256, 256, 0, stream>>>(e0, e1, e2, e3, e4, e5, ebf);
    k_prep_w<12><<<(12 * 16 * 64 + 255) / 256, 256, 0, stream>>>(W1, Wt1);
    k_prep_w<4><<<(4 * 16 * 64 + 255) / 256, 256, 0, stream>>>(W2, Wt2);
    k_hist<<<(ETOT + 255) / 256, 256, 0, stream>>>(ei, deg);
    k_scan1<<<nb, 256, 0, stream>>>(deg, offs, bsum);
    k_scan2<<<1, 64, 0, stream>>>(bsum, nb, offs);
    k_scan3<<<nb, 256, 0, stream>>>(offs, bsum);
    k_scatter<<<(ETOT + 255) / 256, 256, 0, stream>>>(ei, offs, cur, csrc);

    // layer 1
    {
        dim3 grid(4, (NN + 127) / 128);
        k_gemm_mfma<0, 12><<<grid, 256, 0, stream>>>(x, ebf, nullptr, Wt1, xwb, NN);
    }
    k_sd2<2><<<nwb, 256, 0, stream>>>(xwb, as1, ad1, sbuf, dbuf);
    k_agg1<<<nwb, 256, 0, stream>>>(xwb, sbuf, dbuf, offs, csrc, b1, h1b);

    // layer 2
    {
        dim3 grid(4, (NN + 127) / 128);
        k_gemm_mfma<1, 4><<<grid, 256, 0, stream>>>(x, ebf, h1b, Wt2, xwb, NN);
    }
    k_sd2<4><<<nwb, 256, 0, stream>>>(xwb, as2, ad2, sbuf, dbuf);
    k_agg2<<<nwb, 256, 0, stream>>>(xwb, sbuf, dbuf, offs, csrc, b2, bat, gsum);

    // final
    k_final<<<GG, 64, 0, stream>>>(gsum, lw, lb, out);
}